// Round 7
// baseline (190.540 us; speedup 1.0000x reference)
//
#include <hip/hip_runtime.h>

// VQ-VAE vector quantizer — R12.
// R11b post-mortem: LDS B-staging near-null (98->93us). Five schedule variants
// (R6 83.7 / R8 98 / R9 101 / R11 93) all land 83-101us => the K-loop schedule
// is not the bottleneck. Invariant: 8192 waves x (128KB B + 1.9K VALU + 192
// MFMA); per-CU LDS-port service alone ~20us; 8 blocks/CU of work at ~4-block
// residency = 2 rounds + tail.
// R12: rows-per-wave 16 -> 32 (2 row-tiles/wave, ROWS_=128, NBLK_=1024):
//  - wave count halves -> B-bytes through LDS port halve (~20 -> ~10us);
//  - per-CU work = 4 blocks = VGPR-limited residency -> ONE round, no tail;
//  - barriers/stage per MFMA halve; B global fetch halves.
//  - VALU/MFMA totals unchanged; per-chain MFMA order identical (same numerics).
//  - VGPR ~110-125 expected (4 waves/SIMD band); NO launch_bounds 2nd arg (R10).

#define B_ 32
#define C_ 64
#define HW_ 4096
#define K_ 512
#define N_ (B_ * HW_)
#define NC_ ((long long)N_ * C_)
#define ROWS_ 128
#define NBLK_ (N_ / ROWS_)     // 1024
#define NSLOT_ 8

typedef __attribute__((ext_vector_type(8))) short short8;
typedef __attribute__((ext_vector_type(4))) float float4_t;

// ---- workspace layout (bytes) ----
// 56      float  snmax               4*max_k ||e_k||^2
// 2112    float  en[512]
// 4160    float  embT32[512*64]      exact fp32 emb, [code][c]
// 135232  ushort fBhi[512*64]        bf16 hi of (-2e), fragment-linear
// 200768  ushort fBlo[512*64]        bf16 lo of (-2e), fragment-linear
// 266304  int    ghist8[8*512]       slotted histogram (16 KB)
// 282688  double ssepart[1024]       (8 KB) -> end 290880

__device__ __forceinline__ unsigned short f2bf(float f) {
    unsigned u = __float_as_uint(f);
    u += 0x7fffu + ((u >> 16) & 1u);   // RNE
    return (unsigned short)(u >> 16);
}
__device__ __forceinline__ float bf2f(unsigned short h) {
    return __uint_as_float(((unsigned)h) << 16);
}
__device__ __forceinline__ void merge2(float& m1, int& i1, float& m2,
                                       float om1, int oi1, float om2) {
    if (om1 < m1) { m2 = fminf(m1, om2); m1 = om1; i1 = oi1; }
    else          { m2 = fminf(m2, om1); }
}

// ---------------- prologue ----------------
__global__ __launch_bounds__(512) void vq_init(const float* __restrict__ emb,
                                               float* __restrict__ snmax_p,
                                               float* __restrict__ en,
                                               float* __restrict__ embT32,
                                               unsigned short* __restrict__ fBhi,
                                               unsigned short* __restrict__ fBlo,
                                               int* __restrict__ ghist8) {
    __shared__ float smax[8];
    int k = threadIdx.x;                  // code 0..511
    if (blockIdx.x < 64) {
        int c = blockIdx.x;
        float e = emb[c * K_ + k];        // coalesced over k
        embT32[k * C_ + c] = e;
        float s = -2.0f * e;
        unsigned short hi = f2bf(s);
        unsigned short lo = f2bf(s - bf2f(hi));
        // fragment-linear: fb = [k>>5][(k>>4)&1][c>>5], then lane, then 8 k
        int kk   = c >> 5;
        int lane = (((c & 31) >> 3) << 4) + (k & 15);
        int fb   = ((k >> 5) << 2) + (((k >> 4) & 1) << 1) + kk;
        int off  = (fb << 9) + (lane << 3) + (c & 7);
        fBhi[off] = hi;
        fBlo[off] = lo;
    } else {
        // zero slotted histogram (re-done every graph replay)
#pragma unroll
        for (int s8 = 0; s8 < NSLOT_; ++s8) ghist8[(s8 << 9) + k] = 0;
        float s = 0.f;
#pragma unroll
        for (int c = 0; c < C_; ++c) {
            float e = emb[c * K_ + k];
            s += e * e;
        }
        en[k] = s;
        float m = s;
#pragma unroll
        for (int off = 32; off > 0; off >>= 1)
            m = fmaxf(m, __shfl_down(m, off, 64));
        if ((k & 63) == 0) smax[k >> 6] = m;
        __syncthreads();
        if (k == 0) {
            float mm = smax[0];
#pragma unroll
            for (int w2 = 1; w2 < 8; ++w2) mm = fmaxf(mm, smax[w2]);
            *snmax_p = 4.0f * mm;
        }
    }
}

// stage one p-tile (8KB: 2048 hi + 2048 lo entries) into LDS buffer bufi.
// wave w covers entries [w*512, w*512+512) of each; lane*16B linear dest.
#define STAGE(bufi, pp) do {                                                   \
    int eoff_ = ((pp) << 11) + (w << 9) + (lane << 3);                         \
    __builtin_amdgcn_global_load_lds(                                          \
        (const __attribute__((address_space(1))) unsigned*)(fBhi + eoff_),     \
        (__attribute__((address_space(3))) unsigned*)&LB[bufi][0][(w << 9)],   \
        16, 0, 0);                                                             \
    __builtin_amdgcn_global_load_lds(                                          \
        (const __attribute__((address_space(1))) unsigned*)(fBlo + eoff_),     \
        (__attribute__((address_space(3))) unsigned*)&LB[bufi][1][(w << 9)],   \
        16, 0, 0);                                                             \
} while (0)

// compute one p-tile from LDS buffer bufi; B frags shared across 2 row-tiles.
// Per-chain MFMA order identical to R11 (same numerics per row).
#define COMP_LDS(bufi, pp) do {                                                \
    const unsigned short* hb_ = &LB[bufi][0][lane << 3];                       \
    const unsigned short* lb_ = &LB[bufi][1][lane << 3];                       \
    short8 h0_ = *(const short8*)(hb_);                                        \
    short8 h1_ = *(const short8*)(hb_ + 512);                                  \
    short8 g0_ = *(const short8*)(hb_ + 1024);                                 \
    short8 g1_ = *(const short8*)(hb_ + 1536);                                 \
    short8 l0_ = *(const short8*)(lb_);                                        \
    short8 l1_ = *(const short8*)(lb_ + 512);                                  \
    short8 q0_ = *(const short8*)(lb_ + 1024);                                 \
    short8 q1_ = *(const short8*)(lb_ + 1536);                                 \
    const int cb_ = ((pp) << 5) + ln15;                                        \
    float env0_ = sEn[cb_];                                                    \
    float env1_ = sEn[cb_ + 16];                                               \
    _Pragma("unroll")                                                          \
    for (int rt = 0; rt < 2; ++rt) {                                           \
        float4_t a0 = {env0_, env0_, env0_, env0_};                            \
        float4_t a1 = {0.f, 0.f, 0.f, 0.f};                                    \
        float4_t b0 = {env1_, env1_, env1_, env1_};                            \
        float4_t b1 = {0.f, 0.f, 0.f, 0.f};                                    \
        a0 = __builtin_amdgcn_mfma_f32_16x16x32_bf16(al0[rt], h0_, a0, 0,0,0); \
        a1 = __builtin_amdgcn_mfma_f32_16x16x32_bf16(al1[rt], h1_, a1, 0,0,0); \
        b0 = __builtin_amdgcn_mfma_f32_16x16x32_bf16(al0[rt], g0_, b0, 0,0,0); \
        b1 = __builtin_amdgcn_mfma_f32_16x16x32_bf16(al1[rt], g1_, b1, 0,0,0); \
        a0 = __builtin_amdgcn_mfma_f32_16x16x32_bf16(ah0[rt], l0_, a0, 0,0,0); \
        a1 = __builtin_amdgcn_mfma_f32_16x16x32_bf16(ah1[rt], l1_, a1, 0,0,0); \
        b0 = __builtin_amdgcn_mfma_f32_16x16x32_bf16(ah0[rt], q0_, b0, 0,0,0); \
        b1 = __builtin_amdgcn_mfma_f32_16x16x32_bf16(ah1[rt], q1_, b1, 0,0,0); \
        a0 = __builtin_amdgcn_mfma_f32_16x16x32_bf16(ah0[rt], h0_, a0, 0,0,0); \
        a1 = __builtin_amdgcn_mfma_f32_16x16x32_bf16(ah1[rt], h1_, a1, 0,0,0); \
        b0 = __builtin_amdgcn_mfma_f32_16x16x32_bf16(ah0[rt], g0_, b0, 0,0,0); \
        b1 = __builtin_amdgcn_mfma_f32_16x16x32_bf16(ah1[rt], g1_, b1, 0,0,0); \
        _Pragma("unroll")                                                      \
        for (int reg = 0; reg < 4; ++reg) {                                    \
            float vv = a0[reg] + a1[reg];                                      \
            bool  lt = vv < m1[rt][reg];                                       \
            float mx = fmaxf(vv, m1[rt][reg]);                                 \
            m2[rt][reg] = fminf(m2[rt][reg], mx);                              \
            m1[rt][reg] = fminf(m1[rt][reg], vv);                              \
            i1[rt][reg] = lt ? cb_ : i1[rt][reg];                              \
        }                                                                      \
        _Pragma("unroll")                                                      \
        for (int reg = 0; reg < 4; ++reg) {                                    \
            float vv = b0[reg] + b1[reg];                                      \
            bool  lt = vv < m1[rt][reg];                                       \
            float mx = fmaxf(vv, m1[rt][reg]);                                 \
            m2[rt][reg] = fminf(m2[rt][reg], mx);                              \
            m1[rt][reg] = fminf(m1[rt][reg], vv);                              \
            i1[rt][reg] = lt ? (cb_ + 16) : i1[rt][reg];                       \
        }                                                                      \
    }                                                                          \
} while (0)

// ---------------- main kernel: argmin + q + SSE + slotted hist ----------------
__global__ __launch_bounds__(256) void vq_argmin(const float* __restrict__ x,
                                                 const float* __restrict__ en_g,
                                                 const float* __restrict__ embT32,
                                                 const unsigned short* __restrict__ fBhi,
                                                 const unsigned short* __restrict__ fBlo,
                                                 const float* __restrict__ snmax_p,
                                                 float* __restrict__ out_q,
                                                 float* __restrict__ out_idx,
                                                 int* __restrict__ ghist8,
                                                 double* __restrict__ ssepart) {
    __shared__ unsigned short LB[2][2][2048];    // 16 KB: [buf][hi/lo][entries]
    __shared__ float sEn[K_];                    // 2 KB
    __shared__ float znrow[ROWS_];
    __shared__ int   biarr[ROWS_];
    __shared__ int   flaglist[ROWS_];
    __shared__ float wsse[4];
    __shared__ int   nflag;

    const int t    = threadIdx.x;
    const int lane = t & 63;
    const int w    = t >> 6;             // wave owns rows [w*32, w*32+32)
    const int ln15 = lane & 15;
    const int quad = lane >> 4;
    const int n0   = blockIdx.x * ROWS_;
    const int b    = n0 >> 12;
    const int hw0  = n0 & 4095;
    const float* xbase = x + ((size_t)b << 18) + hw0;

    if (t == 0) nflag = 0;
    sEn[t]       = en_g[t];
    sEn[256 + t] = en_g[256 + t];

    // ---- issue B staging for p=0,1 NOW (drained by the pre-loop barrier,
    //      latency hidden under x load + conversions) ----
    STAGE(0, 0);
    STAGE(1, 1);

    // ---- direct A-fragment load, 2 row-tiles per wave:
    //      lane holds row = w*32 + rt*16 + ln15, c = quad*8+j (+32) ----
    short8 ah0[2], al0[2], ah1[2], al1[2];
#pragma unroll
    for (int rt = 0; rt < 2; ++rt) {
        const int mr = (w << 5) + (rt << 4) + ln15;
        float v0[8], v1[8];
#pragma unroll
        for (int j = 0; j < 8; ++j) {
            v0[j] = xbase[((size_t)((quad << 3) + j) << 12) + mr];
            v1[j] = xbase[((size_t)(32 + (quad << 3) + j) << 12) + mr];
        }
        float znacc = 0.f;
#pragma unroll
        for (int j = 0; j < 8; ++j) {
            unsigned short h0 = f2bf(v0[j]);
            ah0[rt][j] = (short)h0;
            al0[rt][j] = (short)f2bf(v0[j] - bf2f(h0));
            unsigned short h1 = f2bf(v1[j]);
            ah1[rt][j] = (short)h1;
            al1[rt][j] = (short)f2bf(v1[j] - bf2f(h1));
            znacc += v0[j] * v0[j] + v1[j] * v1[j];
        }
        znacc += __shfl_xor(znacc, 16, 64);
        znacc += __shfl_xor(znacc, 32, 64);
        if (quad == 0) znrow[mr] = znacc;
    }
    __syncthreads();     // sEn + znrow + nflag visible; stages 0,1 drained

    const float snm = *snmax_p;

    // ---- stream 512 codes: 16 p-tiles, LDS double-buffered B (block-shared) ----
    float m1[2][4], m2[2][4];
    int   i1[2][4];
#pragma unroll
    for (int rt = 0; rt < 2; ++rt)
#pragma unroll
        for (int reg = 0; reg < 4; ++reg) {
            m1[rt][reg] = 3.4e38f; m2[rt][reg] = 3.4e38f; i1[rt][reg] = 0;
        }

#pragma unroll 2
    for (int p = 0; p < 16; ++p) {
        const int bufi = p & 1;
        COMP_LDS(bufi, p);
        __syncthreads();               // all waves done reading buf[p&1];
                                       // also drains stage(p+1) issued last iter
        if (p < 14) STAGE(bufi, p + 2);
    }

    // ---- 16-lane butterfly finalize + flag decision ----
#pragma unroll
    for (int rt = 0; rt < 2; ++rt)
#pragma unroll
    for (int reg = 0; reg < 4; ++reg) {
        float a1v = m1[rt][reg], a2v = m2[rt][reg];
        int   ai  = i1[rt][reg];
#pragma unroll
        for (int s = 1; s < 16; s <<= 1) {
            float o1 = __shfl_xor(a1v, s, 16);
            int   oi = __shfl_xor(ai, s, 16);
            float o2 = __shfl_xor(a2v, s, 16);
            merge2(a1v, ai, a2v, o1, oi, o2);
        }
        if (ln15 == 0) {
            int row = (w << 5) + (rt << 4) + (quad << 2) + reg;
            float znr = znrow[row];
            float W = 1.4e-4f * __builtin_sqrtf(znr * snm) + 1e-3f;  // sound 2x err bound
            biarr[row] = ai;
            if (a2v > a1v + W) {          // gap > W => approx argmin == exact argmin
                out_idx[n0 + row] = (float)ai;
            } else {
                int pos = atomicAdd(&nflag, 1);   // LDS atomic
                flaglist[pos] = row;
            }
        }
    }
    __syncthreads();

    // ---- exact fp32 rescue (one wave per flagged row; ~1% of rows) ----
    int nf = nflag;
    for (int f = w; f < nf; f += 4) {
        int r = flaglist[f];
        float zl = xbase[((size_t)lane << 12) + r];   // exact z[lane], L2-hot
        float d[8];
#pragma unroll
        for (int j = 0; j < 8; ++j) d[j] = 0.f;
        for (int c4 = 0; c4 < 16; ++c4) {
            float z0 = __shfl(zl, (c4 << 2) + 0, 64);
            float z1 = __shfl(zl, (c4 << 2) + 1, 64);
            float z2 = __shfl(zl, (c4 << 2) + 2, 64);
            float z3 = __shfl(zl, (c4 << 2) + 3, 64);
#pragma unroll
            for (int j = 0; j < 8; ++j) {
                float4_t e = *(const float4_t*)(embT32 + ((((lane << 3) + j) << 6) + (c4 << 2)));
                d[j] = fmaf(z0, e[0], d[j]);
                d[j] = fmaf(z1, e[1], d[j]);
                d[j] = fmaf(z2, e[2], d[j]);
                d[j] = fmaf(z3, e[3], d[j]);
            }
        }
        float znr = znrow[r];
        float best = 3.4e38f;
        int   bidx = 0;
#pragma unroll
        for (int j = 0; j < 8; ++j) {
            int k = (lane << 3) + j;
            float dist = (znr + sEn[k]) - 2.f * d[j];   // reference eval order
            if (dist < best) { best = dist; bidx = k; }
        }
#pragma unroll
        for (int off = 32; off > 0; off >>= 1) {
            float ov = __shfl_down(best, off, 64);
            int   oi = __shfl_down(bidx, off, 64);
            if (ov < best || (ov == best && oi < bidx)) { best = ov; bidx = oi; }
        }
        if (lane == 0) {
            biarr[r] = bidx;
            out_idx[n0 + r] = (float)bidx;
        }
    }
    __syncthreads();

    // ---- phase 2 (register-based), per row-tile ----
    float sacc = 0.f;
#pragma unroll
    for (int rt = 0; rt < 2; ++rt) {
        const int mr   = (w << 5) + (rt << 4) + ln15;
        const int code = biarr[mr];
        const float* eb = embT32 + (code << 6) + (quad << 3);
        float4_t e0 = *(const float4_t*)(eb);          // c = quad*8 + 0..3
        float4_t e1 = *(const float4_t*)(eb + 4);      // c = quad*8 + 4..7
        float4_t e2 = *(const float4_t*)(eb + 32);     // c = 32 + quad*8 + 0..3
        float4_t e3 = *(const float4_t*)(eb + 36);     // c = 32 + quad*8 + 4..7
        float* qrow = out_q + ((size_t)b << 18) + hw0 + mr;
#pragma unroll
        for (int j = 0; j < 4; ++j) {
            int c0 = (quad << 3) + j;
            int c1 = (quad << 3) + 4 + j;
            float zA = bf2f((unsigned short)ah0[rt][j])     + bf2f((unsigned short)al0[rt][j]);
            float zB = bf2f((unsigned short)ah0[rt][4 + j]) + bf2f((unsigned short)al0[rt][4 + j]);
            float dA = e0[j] - zA, dB = e1[j] - zB;
            sacc += dA * dA + dB * dB;
            qrow[(size_t)c0 << 12] = e0[j];
            qrow[(size_t)c1 << 12] = e1[j];
            float zC = bf2f((unsigned short)ah1[rt][j])     + bf2f((unsigned short)al1[rt][j]);
            float zD = bf2f((unsigned short)ah1[rt][4 + j]) + bf2f((unsigned short)al1[rt][4 + j]);
            float dC = e2[j] - zC, dD = e3[j] - zD;
            sacc += dC * dC + dD * dD;
            qrow[(size_t)(32 + c0) << 12] = e2[j];
            qrow[(size_t)(32 + c1) << 12] = e3[j];
        }
    }
#pragma unroll
    for (int off = 32; off > 0; off >>= 1)
        sacc += __shfl_down(sacc, off, 64);
    if (lane == 0) wsse[w] = sacc;
    __syncthreads();

    // ---- tail: regular SSE store + slotted relaxed hist atomics (no fence,
    //      no barrier after — ACK wait overlaps wave retirement) ----
    if (t == 0)
        ssepart[blockIdx.x] = (double)wsse[0] + (double)wsse[1]
                            + (double)wsse[2] + (double)wsse[3];
    if (t < ROWS_)
        __hip_atomic_fetch_add(&ghist8[((blockIdx.x & (NSLOT_ - 1)) << 9) + biarr[t]],
                               1, __ATOMIC_RELAXED, __HIP_MEMORY_SCOPE_AGENT);
}

// ---------------- finale: loss + perplexity (1 block) ----------------
__global__ __launch_bounds__(512) void vq_final(const int* __restrict__ ghist8,
                                                const double* __restrict__ ssepart,
                                                float* __restrict__ out_loss,
                                                float* __restrict__ out_perp) {
    __shared__ float  wsf[8];
    __shared__ double wsd[8];
    int t = threadIdx.x;
    int hsum = 0;
#pragma unroll
    for (int s8 = 0; s8 < NSLOT_; ++s8)
        hsum += ghist8[(s8 << 9) + t];    // coalesced over t
    float p = (float)hsum / (float)N_;
    float s = p * logf(p + 1e-10f);
    double d = ssepart[t] + ssepart[t + 512];          // NBLK_ = 1024
#pragma unroll
    for (int off = 32; off > 0; off >>= 1) {
        s += __shfl_down(s, off, 64);
        d += __shfl_down(d, off, 64);
    }
    if ((t & 63) == 0) { wsf[t >> 6] = s; wsd[t >> 6] = d; }
    __syncthreads();
    if (t == 0) {
        float  S = 0.f;
        double D = 0.0;
#pragma unroll
        for (int w = 0; w < 8; ++w) { S += wsf[w]; D += wsd[w]; }
        *out_perp = expf(-S);
        *out_loss = (float)(1.25 * D / (double)NC_);
    }
}

extern "C" void kernel_launch(void* const* d_in, const int* in_sizes, int n_in,
                              void* d_out, int out_size, void* d_ws, size_t ws_size,
                              hipStream_t stream) {
    const float* x   = (const float*)d_in[0];
    const float* emb = (const float*)d_in[1];

    float* out      = (float*)d_out;
    float* out_loss = out;
    float* out_q    = out + 1;
    float* out_perp = out + 1 + (size_t)N_ * C_;
    float* out_idx  = out + 2 + (size_t)N_ * C_;

    char* ws = (char*)d_ws;
    float*          snmax_p  = (float*)(ws + 56);
    float*          en       = (float*)(ws + 2112);
    float*          embT32   = (float*)(ws + 4160);
    unsigned short* fBhi     = (unsigned short*)(ws + 135232);
    unsigned short* fBlo     = (unsigned short*)(ws + 200768);
    int*            ghist8   = (int*)(ws + 266304);
    double*         ssepart  = (double*)(ws + 282688);

    vq_init<<<65, 512, 0, stream>>>(emb, snmax_p, en, embT32, fBhi, fBlo, ghist8);
    vq_argmin<<<NBLK_, 256, 0, stream>>>(x, en, embT32, fBhi, fBlo, snmax_p,
                                         out_q, out_idx, ghist8, ssepart);
    vq_final<<<1, 512, 0, stream>>>(ghist8, ssepart, out_loss, out_perp);
}

// Round 9
// 149.658 us; speedup vs baseline: 1.2732x; 1.2732x over previous
//
#include <hip/hip_runtime.h>

// VQ-VAE vector quantizer — R14.
// R13 post-mortem: FAILED on Output 3 (indices, absmax 508) while loss/q/perp
// PASSED => biarr correct, a few out_idx rows wrong; flag/rescue code textually
// identical to passing R11b => failure is codegen-level in one of R13's two
// changes: (a) ct-split COMP, (b) fused fence-free finale. BISECT:
// R14 = R11b VERBATIM + ct-split COMP only (3 kernels, R11b tail, snm before
// loop). ct-split halves transient B-frag VGPR (32->16) targeting <=64 VGPR
// = 8 waves/SIMD — occupancy is the only lever that has ever moved this
// kernel (time ~ 586 wave-us / waves-per-SIMD across R6-R12).
// If R14 passes: ct-split innocent + VGPR/occupancy data. If it fails:
// ct-split indicted, revert permanently.

#define B_ 32
#define C_ 64
#define HW_ 4096
#define K_ 512
#define N_ (B_ * HW_)
#define NC_ ((long long)N_ * C_)
#define ROWS_ 64
#define NBLK_ (N_ / ROWS_)     // 2048
#define NSLOT_ 8

typedef __attribute__((ext_vector_type(8))) short short8;
typedef __attribute__((ext_vector_type(4))) float float4_t;

// ---- workspace layout (bytes) ----
// 56      float  snmax               4*max_k ||e_k||^2
// 2112    float  en[512]
// 4160    float  embT32[512*64]      exact fp32 emb, [code][c]
// 135232  ushort fBhi[512*64]        bf16 hi of (-2e), fragment-linear
// 200768  ushort fBlo[512*64]        bf16 lo of (-2e), fragment-linear
// 266304  int    ghist8[8*512]       slotted histogram (16 KB)
// 282688  double ssepart[2048]       (16 KB) -> end 299072

__device__ __forceinline__ unsigned short f2bf(float f) {
    unsigned u = __float_as_uint(f);
    u += 0x7fffu + ((u >> 16) & 1u);   // RNE
    return (unsigned short)(u >> 16);
}
__device__ __forceinline__ float bf2f(unsigned short h) {
    return __uint_as_float(((unsigned)h) << 16);
}
__device__ __forceinline__ void merge2(float& m1, int& i1, float& m2,
                                       float om1, int oi1, float om2) {
    if (om1 < m1) { m2 = fminf(m1, om2); m1 = om1; i1 = oi1; }
    else          { m2 = fminf(m2, om1); }
}

// ---------------- prologue ----------------
__global__ __launch_bounds__(512) void vq_init(const float* __restrict__ emb,
                                               float* __restrict__ snmax_p,
                                               float* __restrict__ en,
                                               float* __restrict__ embT32,
                                               unsigned short* __restrict__ fBhi,
                                               unsigned short* __restrict__ fBlo,
                                               int* __restrict__ ghist8) {
    __shared__ float smax[8];
    int k = threadIdx.x;                  // code 0..511
    if (blockIdx.x < 64) {
        int c = blockIdx.x;
        float e = emb[c * K_ + k];        // coalesced over k
        embT32[k * C_ + c] = e;
        float s = -2.0f * e;
        unsigned short hi = f2bf(s);
        unsigned short lo = f2bf(s - bf2f(hi));
        // fragment-linear: fb = [k>>5][(k>>4)&1][c>>5], then lane, then 8 k
        int kk   = c >> 5;
        int lane = (((c & 31) >> 3) << 4) + (k & 15);
        int fb   = ((k >> 5) << 2) + (((k >> 4) & 1) << 1) + kk;
        int off  = (fb << 9) + (lane << 3) + (c & 7);
        fBhi[off] = hi;
        fBlo[off] = lo;
    } else {
        // zero slotted histogram (re-done every graph replay)
#pragma unroll
        for (int s8 = 0; s8 < NSLOT_; ++s8) ghist8[(s8 << 9) + k] = 0;
        float s = 0.f;
#pragma unroll
        for (int c = 0; c < C_; ++c) {
            float e = emb[c * K_ + k];
            s += e * e;
        }
        en[k] = s;
        float m = s;
#pragma unroll
        for (int off = 32; off > 0; off >>= 1)
            m = fmaxf(m, __shfl_down(m, off, 64));
        if ((k & 63) == 0) smax[k >> 6] = m;
        __syncthreads();
        if (k == 0) {
            float mm = smax[0];
#pragma unroll
            for (int w2 = 1; w2 < 8; ++w2) mm = fmaxf(mm, smax[w2]);
            *snmax_p = 4.0f * mm;
        }
    }
}

// stage one p-tile (8KB: 2048 hi + 2048 lo entries) into LDS buffer bufi.
// wave w covers entries [w*512, w*512+512) of each; lane*16B linear dest.
#define STAGE(bufi, pp) do {                                                   \
    int eoff_ = ((pp) << 11) + (w << 9) + (lane << 3);                         \
    __builtin_amdgcn_global_load_lds(                                          \
        (const __attribute__((address_space(1))) unsigned*)(fBhi + eoff_),     \
        (__attribute__((address_space(3))) unsigned*)&LB[bufi][0][(w << 9)],   \
        16, 0, 0);                                                             \
    __builtin_amdgcn_global_load_lds(                                          \
        (const __attribute__((address_space(1))) unsigned*)(fBlo + eoff_),     \
        (__attribute__((address_space(3))) unsigned*)&LB[bufi][1][(w << 9)],   \
        16, 0, 0);                                                             \
} while (0)

// compute one p-tile from LDS buffer bufi, split into two ct-halves to keep
// transient B-frag VGPR at 16 (was 32). Per-chain MFMA accumulation order
// identical to R11b: a0: al0*h0 -> ah0*l0 -> ah0*h0 ; a1: al1*h1 -> ... ;
// same for b-chains. Top-2 update order also identical (a regs then b regs).
#define COMP_LDS(bufi, pp) do {                                                \
    const unsigned short* hb_ = &LB[bufi][0][lane << 3];                       \
    const unsigned short* lb_ = &LB[bufi][1][lane << 3];                       \
    const int cb_ = ((pp) << 5) + ln15;                                        \
    {   /* ---- ct = 0 (codes cb_) ---- */                                     \
        short8 h0_ = *(const short8*)(hb_);                                    \
        short8 h1_ = *(const short8*)(hb_ + 512);                              \
        short8 l0_ = *(const short8*)(lb_);                                    \
        short8 l1_ = *(const short8*)(lb_ + 512);                              \
        float env0_ = sEn[cb_];                                                \
        float4_t a0 = {env0_, env0_, env0_, env0_};                            \
        float4_t a1 = {0.f, 0.f, 0.f, 0.f};                                    \
        a0 = __builtin_amdgcn_mfma_f32_16x16x32_bf16(al0, h0_, a0, 0, 0, 0);   \
        a1 = __builtin_amdgcn_mfma_f32_16x16x32_bf16(al1, h1_, a1, 0, 0, 0);   \
        a0 = __builtin_amdgcn_mfma_f32_16x16x32_bf16(ah0, l0_, a0, 0, 0, 0);   \
        a1 = __builtin_amdgcn_mfma_f32_16x16x32_bf16(ah1, l1_, a1, 0, 0, 0);   \
        a0 = __builtin_amdgcn_mfma_f32_16x16x32_bf16(ah0, h0_, a0, 0, 0, 0);   \
        a1 = __builtin_amdgcn_mfma_f32_16x16x32_bf16(ah1, h1_, a1, 0, 0, 0);   \
        _Pragma("unroll")                                                      \
        for (int reg = 0; reg < 4; ++reg) {                                    \
            float vv = a0[reg] + a1[reg];                                      \
            bool  lt = vv < m1[reg];                                           \
            float mx = fmaxf(vv, m1[reg]);                                     \
            m2[reg] = fminf(m2[reg], mx);                                      \
            m1[reg] = fminf(m1[reg], vv);                                      \
            i1[reg] = lt ? cb_ : i1[reg];                                      \
        }                                                                      \
    }                                                                          \
    {   /* ---- ct = 1 (codes cb_+16) ---- */                                  \
        short8 g0_ = *(const short8*)(hb_ + 1024);                             \
        short8 g1_ = *(const short8*)(hb_ + 1536);                             \
        short8 q0_ = *(const short8*)(lb_ + 1024);                             \
        short8 q1_ = *(const short8*)(lb_ + 1536);                             \
        float env1_ = sEn[cb_ + 16];                                           \
        float4_t b0 = {env1_, env1_, env1_, env1_};                            \
        float4_t b1 = {0.f, 0.f, 0.f, 0.f};                                    \
        b0 = __builtin_amdgcn_mfma_f32_16x16x32_bf16(al0, g0_, b0, 0, 0, 0);   \
        b1 = __builtin_amdgcn_mfma_f32_16x16x32_bf16(al1, g1_, b1, 0, 0, 0);   \
        b0 = __builtin_amdgcn_mfma_f32_16x16x32_bf16(ah0, q0_, b0, 0, 0, 0);   \
        b1 = __builtin_amdgcn_mfma_f32_16x16x32_bf16(ah1, q1_, b1, 0, 0, 0);   \
        b0 = __builtin_amdgcn_mfma_f32_16x16x32_bf16(ah0, g0_, b0, 0, 0, 0);   \
        b1 = __builtin_amdgcn_mfma_f32_16x16x32_bf16(ah1, g1_, b1, 0, 0, 0);   \
        _Pragma("unroll")                                                      \
        for (int reg = 0; reg < 4; ++reg) {                                    \
            float vv = b0[reg] + b1[reg];                                      \
            bool  lt = vv < m1[reg];                                           \
            float mx = fmaxf(vv, m1[reg]);                                     \
            m2[reg] = fminf(m2[reg], mx);                                      \
            m1[reg] = fminf(m1[reg], vv);                                      \
            i1[reg] = lt ? (cb_ + 16) : i1[reg];                               \
        }                                                                      \
    }                                                                          \
} while (0)

// ---------------- main kernel: argmin + q + SSE + slotted hist ----------------
__global__ __launch_bounds__(256) void vq_argmin(const float* __restrict__ x,
                                                 const float* __restrict__ en_g,
                                                 const float* __restrict__ embT32,
                                                 const unsigned short* __restrict__ fBhi,
                                                 const unsigned short* __restrict__ fBlo,
                                                 const float* __restrict__ snmax_p,
                                                 float* __restrict__ out_q,
                                                 float* __restrict__ out_idx,
                                                 int* __restrict__ ghist8,
                                                 double* __restrict__ ssepart) {
    __shared__ unsigned short LB[2][2][2048];    // 16 KB: [buf][hi/lo][entries]
    __shared__ float sEn[K_];                    // 2 KB
    __shared__ float znrow[ROWS_];
    __shared__ int   biarr[ROWS_];
    __shared__ int   flaglist[ROWS_];
    __shared__ float wsse[4];
    __shared__ int   nflag;

    const int t    = threadIdx.x;
    const int lane = t & 63;
    const int w    = t >> 6;             // wave owns row-tile w (rows w*16..+15)
    const int ln15 = lane & 15;
    const int quad = lane >> 4;
    const int n0   = blockIdx.x * ROWS_;
    const int b    = n0 >> 12;
    const int hw0  = n0 & 4095;
    const float* xbase = x + ((size_t)b << 18) + hw0;
    const int myrow = (w << 4) + ln15;

    if (t == 0) nflag = 0;
    sEn[t]       = en_g[t];
    sEn[256 + t] = en_g[256 + t];

    // ---- issue B staging for p=0,1 NOW (drained by the pre-loop barrier,
    //      latency hidden under x load + conversions) ----
    STAGE(0, 0);
    STAGE(1, 1);

    // ---- direct A-fragment load: lane holds row=myrow, c = quad*8+j (+32) ----
    float v0[8], v1[8];
#pragma unroll
    for (int j = 0; j < 8; ++j) {
        v0[j] = xbase[((size_t)((quad << 3) + j) << 12) + myrow];
        v1[j] = xbase[((size_t)(32 + (quad << 3) + j) << 12) + myrow];
    }
    short8 ah0, al0, ah1, al1;
    float znacc = 0.f;
#pragma unroll
    for (int j = 0; j < 8; ++j) {
        unsigned short h0 = f2bf(v0[j]);
        ah0[j] = (short)h0;
        al0[j] = (short)f2bf(v0[j] - bf2f(h0));
        unsigned short h1 = f2bf(v1[j]);
        ah1[j] = (short)h1;
        al1[j] = (short)f2bf(v1[j] - bf2f(h1));
        znacc += v0[j] * v0[j] + v1[j] * v1[j];
    }
    // full ||z_row||^2: reduce over the 4 quads holding the same row
    znacc += __shfl_xor(znacc, 16, 64);
    znacc += __shfl_xor(znacc, 32, 64);
    if (quad == 0) znrow[myrow] = znacc;
    __syncthreads();     // sEn + znrow + nflag visible; stages 0,1 drained

    const float snm = *snmax_p;

    // ---- stream 512 codes: 16 p-tiles, LDS double-buffered B (block-shared) ----
    float m1[4], m2[4];
    int   i1[4];
#pragma unroll
    for (int reg = 0; reg < 4; ++reg) {
        m1[reg] = 3.4e38f; m2[reg] = 3.4e38f; i1[reg] = 0;
    }

#pragma unroll 2
    for (int p = 0; p < 16; ++p) {
        const int bufi = p & 1;
        COMP_LDS(bufi, p);
        __syncthreads();               // all waves done reading buf[p&1];
                                       // also drains stage(p+1) issued last iter
        if (p < 14) STAGE(bufi, p + 2);
    }

    // ---- 16-lane butterfly finalize + flag decision ----
#pragma unroll
    for (int reg = 0; reg < 4; ++reg) {
        float a1v = m1[reg], a2v = m2[reg];
        int   ai  = i1[reg];
#pragma unroll
        for (int s = 1; s < 16; s <<= 1) {
            float o1 = __shfl_xor(a1v, s, 16);
            int   oi = __shfl_xor(ai, s, 16);
            float o2 = __shfl_xor(a2v, s, 16);
            merge2(a1v, ai, a2v, o1, oi, o2);
        }
        if (ln15 == 0) {
            int row = (w << 4) + (quad << 2) + reg;
            float znr = znrow[row];
            float W = 1.4e-4f * __builtin_sqrtf(znr * snm) + 1e-3f;  // sound 2x err bound
            biarr[row] = ai;
            if (a2v > a1v + W) {          // gap > W => approx argmin == exact argmin
                out_idx[n0 + row] = (float)ai;
            } else {
                int pos = atomicAdd(&nflag, 1);   // LDS atomic
                flaglist[pos] = row;
            }
        }
    }
    __syncthreads();

    // ---- exact fp32 rescue (one wave per flagged row; ~1% of rows) ----
    int nf = nflag;
    for (int f = w; f < nf; f += 4) {
        int r = flaglist[f];
        float zl = xbase[((size_t)lane << 12) + r];   // exact z[lane], L2-hot
        float d[8];
#pragma unroll
        for (int j = 0; j < 8; ++j) d[j] = 0.f;
        for (int c4 = 0; c4 < 16; ++c4) {
            float z0 = __shfl(zl, (c4 << 2) + 0, 64);
            float z1 = __shfl(zl, (c4 << 2) + 1, 64);
            float z2 = __shfl(zl, (c4 << 2) + 2, 64);
            float z3 = __shfl(zl, (c4 << 2) + 3, 64);
#pragma unroll
            for (int j = 0; j < 8; ++j) {
                float4_t e = *(const float4_t*)(embT32 + ((((lane << 3) + j) << 6) + (c4 << 2)));
                d[j] = fmaf(z0, e[0], d[j]);
                d[j] = fmaf(z1, e[1], d[j]);
                d[j] = fmaf(z2, e[2], d[j]);
                d[j] = fmaf(z3, e[3], d[j]);
            }
        }
        float znr = znrow[r];
        float best = 3.4e38f;
        int   bidx = 0;
#pragma unroll
        for (int j = 0; j < 8; ++j) {
            int k = (lane << 3) + j;
            float dist = (znr + sEn[k]) - 2.f * d[j];   // reference eval order
            if (dist < best) { best = dist; bidx = k; }
        }
#pragma unroll
        for (int off = 32; off > 0; off >>= 1) {
            float ov = __shfl_down(best, off, 64);
            int   oi = __shfl_down(bidx, off, 64);
            if (ov < best || (ov == best && oi < bidx)) { best = ov; bidx = oi; }
        }
        if (lane == 0) {
            biarr[r] = bidx;
            out_idx[n0 + r] = (float)bidx;
        }
    }
    __syncthreads();

    // ---- phase 2 (register-based): lane covers row = myrow, c = quad*8+j (+32) ----
    const int code  = biarr[myrow];
    const float* eb = embT32 + (code << 6) + (quad << 3);
    float4_t e0 = *(const float4_t*)(eb);          // c = quad*8 + 0..3
    float4_t e1 = *(const float4_t*)(eb + 4);      // c = quad*8 + 4..7
    float4_t e2 = *(const float4_t*)(eb + 32);     // c = 32 + quad*8 + 0..3
    float4_t e3 = *(const float4_t*)(eb + 36);     // c = 32 + quad*8 + 4..7
    float* qrow = out_q + ((size_t)b << 18) + hw0 + myrow;
    float sacc = 0.f;
#pragma unroll
    for (int j = 0; j < 4; ++j) {
        int c0 = (quad << 3) + j;
        int c1 = (quad << 3) + 4 + j;
        // chunk 0 (c < 32): frags ah0/al0
        float zA = bf2f((unsigned short)ah0[j])     + bf2f((unsigned short)al0[j]);
        float zB = bf2f((unsigned short)ah0[4 + j]) + bf2f((unsigned short)al0[4 + j]);
        float dA = e0[j] - zA, dB = e1[j] - zB;
        sacc += dA * dA + dB * dB;
        qrow[(size_t)c0 << 12] = e0[j];
        qrow[(size_t)c1 << 12] = e1[j];
        // chunk 1 (c >= 32): frags ah1/al1
        float zC = bf2f((unsigned short)ah1[j])     + bf2f((unsigned short)al1[j]);
        float zD = bf2f((unsigned short)ah1[4 + j]) + bf2f((unsigned short)al1[4 + j]);
        float dC = e2[j] - zC, dD = e3[j] - zD;
        sacc += dC * dC + dD * dD;
        qrow[(size_t)(32 + c0) << 12] = e2[j];
        qrow[(size_t)(32 + c1) << 12] = e3[j];
    }
#pragma unroll
    for (int off = 32; off > 0; off >>= 1)
        sacc += __shfl_down(sacc, off, 64);
    if (lane == 0) wsse[w] = sacc;
    __syncthreads();

    // ---- tail: regular SSE store + slotted relaxed hist atomics (no fence,
    //      no barrier after — ACK wait overlaps wave retirement) ----
    if (t == 0)
        ssepart[blockIdx.x] = (double)wsse[0] + (double)wsse[1]
                            + (double)wsse[2] + (double)wsse[3];
    if (t < ROWS_)
        __hip_atomic_fetch_add(&ghist8[((blockIdx.x & (NSLOT_ - 1)) << 9) + biarr[t]],
                               1, __ATOMIC_RELAXED, __HIP_MEMORY_SCOPE_AGENT);
}

// ---------------- finale: loss + perplexity (1 block) ----------------
__global__ __launch_bounds__(512) void vq_final(const int* __restrict__ ghist8,
                                                const double* __restrict__ ssepart,
                                                float* __restrict__ out_loss,
                                                float* __restrict__ out_perp) {
    __shared__ float  wsf[8];
    __shared__ double wsd[8];
    int t = threadIdx.x;
    int hsum = 0;
#pragma unroll
    for (int s8 = 0; s8 < NSLOT_; ++s8)
        hsum += ghist8[(s8 << 9) + t];    // coalesced over t
    float p = (float)hsum / (float)N_;
    float s = p * logf(p + 1e-10f);
    double d = ssepart[t] + ssepart[t + 512] + ssepart[t + 1024] + ssepart[t + 1536];
#pragma unroll
    for (int off = 32; off > 0; off >>= 1) {
        s += __shfl_down(s, off, 64);
        d += __shfl_down(d, off, 64);
    }
    if ((t & 63) == 0) { wsf[t >> 6] = s; wsd[t >> 6] = d; }
    __syncthreads();
    if (t == 0) {
        float  S = 0.f;
        double D = 0.0;
#pragma unroll
        for (int w = 0; w < 8; ++w) { S += wsf[w]; D += wsd[w]; }
        *out_perp = expf(-S);
        *out_loss = (float)(1.25 * D / (double)NC_);
    }
}

extern "C" void kernel_launch(void* const* d_in, const int* in_sizes, int n_in,
                              void* d_out, int out_size, void* d_ws, size_t ws_size,
                              hipStream_t stream) {
    const float* x   = (const float*)d_in[0];
    const float* emb = (const float*)d_in[1];

    float* out      = (float*)d_out;
    float* out_loss = out;
    float* out_q    = out + 1;
    float* out_perp = out + 1 + (size_t)N_ * C_;
    float* out_idx  = out + 2 + (size_t)N_ * C_;

    char* ws = (char*)d_ws;
    float*          snmax_p  = (float*)(ws + 56);
    float*          en       = (float*)(ws + 2112);
    float*          embT32   = (float*)(ws + 4160);
    unsigned short* fBhi     = (unsigned short*)(ws + 135232);
    unsigned short* fBlo     = (unsigned short*)(ws + 200768);
    int*            ghist8   = (int*)(ws + 266304);
    double*         ssepart  = (double*)(ws + 282688);

    vq_init<<<65, 512, 0, stream>>>(emb, snmax_p, en, embT32, fBhi, fBlo, ghist8);
    vq_argmin<<<NBLK_, 256, 0, stream>>>(x, en, embT32, fBhi, fBlo, snmax_p,
                                         out_q, out_idx, ghist8, ssepart);
    vq_final<<<1, 512, 0, stream>>>(ghist8, ssepart, out_loss, out_perp);
}

// Round 10
// 144.930 us; speedup vs baseline: 1.3147x; 1.0326x over previous
//
#include <hip/hip_runtime.h>

// VQ-VAE vector quantizer — R15.
// R14 post-mortem: PASSED 149.7us (best); ct-split innocent (93->84 at same
// VGPR 84) => R13's fused finale indicted, stays reverted. Three different
// K-loop structures converge ~84-98us at 4 waves/SIMD (VGPR band 65-128;
// <=64 unreachable per R10 spills). Per-SIMD: 202Kcy, VALU 66K, MFMA 24K =>
// >50% stalls: 16 per-p-tile barriers convoy all 4 waves into the LDS port
// at once (32x ds_read_b128 ~384cy serialized), then all-MFMA, then all-VALU.
// R15: (1) quad-buffered B staging, ONE barrier per TWO p-tiles (8 loop
// barriers); stages p+4/p+5 issued after the barrier freeing their bufs.
// (2) fmed3-based top-2 (m2'=med3(m1,m2,vv), provably == min(m2,max(m1,vv))).
// COMP per p-tile otherwise identical to R14 => same numerics.

#define B_ 32
#define C_ 64
#define HW_ 4096
#define K_ 512
#define N_ (B_ * HW_)
#define NC_ ((long long)N_ * C_)
#define ROWS_ 64
#define NBLK_ (N_ / ROWS_)     // 2048
#define NSLOT_ 8

typedef __attribute__((ext_vector_type(8))) short short8;
typedef __attribute__((ext_vector_type(4))) float float4_t;

// ---- workspace layout (bytes) ----
// 56      float  snmax               4*max_k ||e_k||^2
// 2112    float  en[512]
// 4160    float  embT32[512*64]      exact fp32 emb, [code][c]
// 135232  ushort fBhi[512*64]        bf16 hi of (-2e), fragment-linear
// 200768  ushort fBlo[512*64]        bf16 lo of (-2e), fragment-linear
// 266304  int    ghist8[8*512]       slotted histogram (16 KB)
// 282688  double ssepart[2048]       (16 KB) -> end 299072

__device__ __forceinline__ unsigned short f2bf(float f) {
    unsigned u = __float_as_uint(f);
    u += 0x7fffu + ((u >> 16) & 1u);   // RNE
    return (unsigned short)(u >> 16);
}
__device__ __forceinline__ float bf2f(unsigned short h) {
    return __uint_as_float(((unsigned)h) << 16);
}
__device__ __forceinline__ void merge2(float& m1, int& i1, float& m2,
                                       float om1, int oi1, float om2) {
    if (om1 < m1) { m2 = fminf(m1, om2); m1 = om1; i1 = oi1; }
    else          { m2 = fminf(m2, om1); }
}

// ---------------- prologue ----------------
__global__ __launch_bounds__(512) void vq_init(const float* __restrict__ emb,
                                               float* __restrict__ snmax_p,
                                               float* __restrict__ en,
                                               float* __restrict__ embT32,
                                               unsigned short* __restrict__ fBhi,
                                               unsigned short* __restrict__ fBlo,
                                               int* __restrict__ ghist8) {
    __shared__ float smax[8];
    int k = threadIdx.x;                  // code 0..511
    if (blockIdx.x < 64) {
        int c = blockIdx.x;
        float e = emb[c * K_ + k];        // coalesced over k
        embT32[k * C_ + c] = e;
        float s = -2.0f * e;
        unsigned short hi = f2bf(s);
        unsigned short lo = f2bf(s - bf2f(hi));
        // fragment-linear: fb = [k>>5][(k>>4)&1][c>>5], then lane, then 8 k
        int kk   = c >> 5;
        int lane = (((c & 31) >> 3) << 4) + (k & 15);
        int fb   = ((k >> 5) << 2) + (((k >> 4) & 1) << 1) + kk;
        int off  = (fb << 9) + (lane << 3) + (c & 7);
        fBhi[off] = hi;
        fBlo[off] = lo;
    } else {
        // zero slotted histogram (re-done every graph replay)
#pragma unroll
        for (int s8 = 0; s8 < NSLOT_; ++s8) ghist8[(s8 << 9) + k] = 0;
        float s = 0.f;
#pragma unroll
        for (int c = 0; c < C_; ++c) {
            float e = emb[c * K_ + k];
            s += e * e;
        }
        en[k] = s;
        float m = s;
#pragma unroll
        for (int off = 32; off > 0; off >>= 1)
            m = fmaxf(m, __shfl_down(m, off, 64));
        if ((k & 63) == 0) smax[k >> 6] = m;
        __syncthreads();
        if (k == 0) {
            float mm = smax[0];
#pragma unroll
            for (int w2 = 1; w2 < 8; ++w2) mm = fmaxf(mm, smax[w2]);
            *snmax_p = 4.0f * mm;
        }
    }
}

// stage one p-tile (8KB: 2048 hi + 2048 lo entries) into LDS buffer bufi.
// wave w covers entries [w*512, w*512+512) of each; lane*16B linear dest.
#define STAGE(bufi, pp) do {                                                   \
    int eoff_ = ((pp) << 11) + (w << 9) + (lane << 3);                         \
    __builtin_amdgcn_global_load_lds(                                          \
        (const __attribute__((address_space(1))) unsigned*)(fBhi + eoff_),     \
        (__attribute__((address_space(3))) unsigned*)&LB[bufi][0][(w << 9)],   \
        16, 0, 0);                                                             \
    __builtin_amdgcn_global_load_lds(                                          \
        (const __attribute__((address_space(1))) unsigned*)(fBlo + eoff_),     \
        (__attribute__((address_space(3))) unsigned*)&LB[bufi][1][(w << 9)],   \
        16, 0, 0);                                                             \
} while (0)

// compute one p-tile from LDS buffer bufi, ct-split (R14-proven). Per-chain
// MFMA order identical to R11b/R14. Top-2 via fmed3: m2'=med3(m1,m2,vv)
// == min(m2, max(m1, vv)) for m1<=m2 (case check: vv<m1 -> m1; m1<=vv<=m2
// -> vv; vv>m2 -> m2). i1 uses lt computed against m1_old.
#define COMP_LDS(bufi, pp) do {                                                \
    const unsigned short* hb_ = &LB[bufi][0][lane << 3];                       \
    const unsigned short* lb_ = &LB[bufi][1][lane << 3];                       \
    const int cb_ = ((pp) << 5) + ln15;                                        \
    {   /* ---- ct = 0 (codes cb_) ---- */                                     \
        short8 h0_ = *(const short8*)(hb_);                                    \
        short8 h1_ = *(const short8*)(hb_ + 512);                              \
        short8 l0_ = *(const short8*)(lb_);                                    \
        short8 l1_ = *(const short8*)(lb_ + 512);                              \
        float env0_ = sEn[cb_];                                                \
        float4_t a0 = {env0_, env0_, env0_, env0_};                            \
        float4_t a1 = {0.f, 0.f, 0.f, 0.f};                                    \
        a0 = __builtin_amdgcn_mfma_f32_16x16x32_bf16(al0, h0_, a0, 0, 0, 0);   \
        a1 = __builtin_amdgcn_mfma_f32_16x16x32_bf16(al1, h1_, a1, 0, 0, 0);   \
        a0 = __builtin_amdgcn_mfma_f32_16x16x32_bf16(ah0, l0_, a0, 0, 0, 0);   \
        a1 = __builtin_amdgcn_mfma_f32_16x16x32_bf16(ah1, l1_, a1, 0, 0, 0);   \
        a0 = __builtin_amdgcn_mfma_f32_16x16x32_bf16(ah0, h0_, a0, 0, 0, 0);   \
        a1 = __builtin_amdgcn_mfma_f32_16x16x32_bf16(ah1, h1_, a1, 0, 0, 0);   \
        _Pragma("unroll")                                                      \
        for (int reg = 0; reg < 4; ++reg) {                                    \
            float vv = a0[reg] + a1[reg];                                      \
            bool  lt = vv < m1[reg];                                           \
            m2[reg] = __builtin_amdgcn_fmed3f(m1[reg], m2[reg], vv);           \
            m1[reg] = fminf(m1[reg], vv);                                      \
            i1[reg] = lt ? cb_ : i1[reg];                                      \
        }                                                                      \
    }                                                                          \
    {   /* ---- ct = 1 (codes cb_+16) ---- */                                  \
        short8 g0_ = *(const short8*)(hb_ + 1024);                             \
        short8 g1_ = *(const short8*)(hb_ + 1536);                             \
        short8 q0_ = *(const short8*)(lb_ + 1024);                             \
        short8 q1_ = *(const short8*)(lb_ + 1536);                             \
        float env1_ = sEn[cb_ + 16];                                           \
        float4_t b0 = {env1_, env1_, env1_, env1_};                            \
        float4_t b1 = {0.f, 0.f, 0.f, 0.f};                                    \
        b0 = __builtin_amdgcn_mfma_f32_16x16x32_bf16(al0, g0_, b0, 0, 0, 0);   \
        b1 = __builtin_amdgcn_mfma_f32_16x16x32_bf16(al1, g1_, b1, 0, 0, 0);   \
        b0 = __builtin_amdgcn_mfma_f32_16x16x32_bf16(ah0, q0_, b0, 0, 0, 0);   \
        b1 = __builtin_amdgcn_mfma_f32_16x16x32_bf16(ah1, q1_, b1, 0, 0, 0);   \
        b0 = __builtin_amdgcn_mfma_f32_16x16x32_bf16(ah0, g0_, b0, 0, 0, 0);   \
        b1 = __builtin_amdgcn_mfma_f32_16x16x32_bf16(ah1, g1_, b1, 0, 0, 0);   \
        _Pragma("unroll")                                                      \
        for (int reg = 0; reg < 4; ++reg) {                                    \
            float vv = b0[reg] + b1[reg];                                      \
            bool  lt = vv < m1[reg];                                           \
            m2[reg] = __builtin_amdgcn_fmed3f(m1[reg], m2[reg], vv);           \
            m1[reg] = fminf(m1[reg], vv);                                      \
            i1[reg] = lt ? (cb_ + 16) : i1[reg];                               \
        }                                                                      \
    }                                                                          \
} while (0)

// ---------------- main kernel: argmin + q + SSE + slotted hist ----------------
__global__ __launch_bounds__(256) void vq_argmin(const float* __restrict__ x,
                                                 const float* __restrict__ en_g,
                                                 const float* __restrict__ embT32,
                                                 const unsigned short* __restrict__ fBhi,
                                                 const unsigned short* __restrict__ fBlo,
                                                 const float* __restrict__ snmax_p,
                                                 float* __restrict__ out_q,
                                                 float* __restrict__ out_idx,
                                                 int* __restrict__ ghist8,
                                                 double* __restrict__ ssepart) {
    __shared__ unsigned short LB[4][2][2048];    // 32 KB: [buf][hi/lo][entries]
    __shared__ float sEn[K_];                    // 2 KB
    __shared__ float znrow[ROWS_];
    __shared__ int   biarr[ROWS_];
    __shared__ int   flaglist[ROWS_];
    __shared__ float wsse[4];
    __shared__ int   nflag;

    const int t    = threadIdx.x;
    const int lane = t & 63;
    const int w    = t >> 6;             // wave owns row-tile w (rows w*16..+15)
    const int ln15 = lane & 15;
    const int quad = lane >> 4;
    const int n0   = blockIdx.x * ROWS_;
    const int b    = n0 >> 12;
    const int hw0  = n0 & 4095;
    const float* xbase = x + ((size_t)b << 18) + hw0;
    const int myrow = (w << 4) + ln15;

    if (t == 0) nflag = 0;
    sEn[t]       = en_g[t];
    sEn[256 + t] = en_g[256 + t];

    // ---- issue B staging for p=0..3 NOW (all drained by the pre-loop
    //      barrier; latency hidden under x load + conversions) ----
    STAGE(0, 0);
    STAGE(1, 1);
    STAGE(2, 2);
    STAGE(3, 3);

    // ---- direct A-fragment load: lane holds row=myrow, c = quad*8+j (+32) ----
    float v0[8], v1[8];
#pragma unroll
    for (int j = 0; j < 8; ++j) {
        v0[j] = xbase[((size_t)((quad << 3) + j) << 12) + myrow];
        v1[j] = xbase[((size_t)(32 + (quad << 3) + j) << 12) + myrow];
    }
    short8 ah0, al0, ah1, al1;
    float znacc = 0.f;
#pragma unroll
    for (int j = 0; j < 8; ++j) {
        unsigned short h0 = f2bf(v0[j]);
        ah0[j] = (short)h0;
        al0[j] = (short)f2bf(v0[j] - bf2f(h0));
        unsigned short h1 = f2bf(v1[j]);
        ah1[j] = (short)h1;
        al1[j] = (short)f2bf(v1[j] - bf2f(h1));
        znacc += v0[j] * v0[j] + v1[j] * v1[j];
    }
    // full ||z_row||^2: reduce over the 4 quads holding the same row
    znacc += __shfl_xor(znacc, 16, 64);
    znacc += __shfl_xor(znacc, 32, 64);
    if (quad == 0) znrow[myrow] = znacc;
    __syncthreads();     // sEn + znrow + nflag visible; stages 0..3 drained

    const float snm = *snmax_p;

    // ---- stream 512 codes: 16 p-tiles, quad-buffered B, 1 barrier / 2 tiles ----
    float m1[4], m2[4];
    int   i1[4];
#pragma unroll
    for (int reg = 0; reg < 4; ++reg) {
        m1[reg] = 3.4e38f; m2[reg] = 3.4e38f; i1[reg] = 0;
    }

    for (int p = 0; p < 16; p += 2) {
        COMP_LDS(p & 3, p);
        COMP_LDS((p + 1) & 3, p + 1);
        __syncthreads();               // waves done reading bufs p, p+1;
                                       // drains stages p+2, p+3 (issued earlier)
        if (p < 12) {
            STAGE(p & 3, p + 4);       // into just-freed bufs
            STAGE((p + 1) & 3, p + 5);
        }
    }

    // ---- 16-lane butterfly finalize + flag decision ----
#pragma unroll
    for (int reg = 0; reg < 4; ++reg) {
        float a1v = m1[reg], a2v = m2[reg];
        int   ai  = i1[reg];
#pragma unroll
        for (int s = 1; s < 16; s <<= 1) {
            float o1 = __shfl_xor(a1v, s, 16);
            int   oi = __shfl_xor(ai, s, 16);
            float o2 = __shfl_xor(a2v, s, 16);
            merge2(a1v, ai, a2v, o1, oi, o2);
        }
        if (ln15 == 0) {
            int row = (w << 4) + (quad << 2) + reg;
            float znr = znrow[row];
            float W = 1.4e-4f * __builtin_sqrtf(znr * snm) + 1e-3f;  // sound 2x err bound
            biarr[row] = ai;
            if (a2v > a1v + W) {          // gap > W => approx argmin == exact argmin
                out_idx[n0 + row] = (float)ai;
            } else {
                int pos = atomicAdd(&nflag, 1);   // LDS atomic
                flaglist[pos] = row;
            }
        }
    }
    __syncthreads();

    // ---- exact fp32 rescue (one wave per flagged row; ~1% of rows) ----
    int nf = nflag;
    for (int f = w; f < nf; f += 4) {
        int r = flaglist[f];
        float zl = xbase[((size_t)lane << 12) + r];   // exact z[lane], L2-hot
        float d[8];
#pragma unroll
        for (int j = 0; j < 8; ++j) d[j] = 0.f;
        for (int c4 = 0; c4 < 16; ++c4) {
            float z0 = __shfl(zl, (c4 << 2) + 0, 64);
            float z1 = __shfl(zl, (c4 << 2) + 1, 64);
            float z2 = __shfl(zl, (c4 << 2) + 2, 64);
            float z3 = __shfl(zl, (c4 << 2) + 3, 64);
#pragma unroll
            for (int j = 0; j < 8; ++j) {
                float4_t e = *(const float4_t*)(embT32 + ((((lane << 3) + j) << 6) + (c4 << 2)));
                d[j] = fmaf(z0, e[0], d[j]);
                d[j] = fmaf(z1, e[1], d[j]);
                d[j] = fmaf(z2, e[2], d[j]);
                d[j] = fmaf(z3, e[3], d[j]);
            }
        }
        float znr = znrow[r];
        float best = 3.4e38f;
        int   bidx = 0;
#pragma unroll
        for (int j = 0; j < 8; ++j) {
            int k = (lane << 3) + j;
            float dist = (znr + sEn[k]) - 2.f * d[j];   // reference eval order
            if (dist < best) { best = dist; bidx = k; }
        }
#pragma unroll
        for (int off = 32; off > 0; off >>= 1) {
            float ov = __shfl_down(best, off, 64);
            int   oi = __shfl_down(bidx, off, 64);
            if (ov < best || (ov == best && oi < bidx)) { best = ov; bidx = oi; }
        }
        if (lane == 0) {
            biarr[r] = bidx;
            out_idx[n0 + r] = (float)bidx;
        }
    }
    __syncthreads();

    // ---- phase 2 (register-based): lane covers row = myrow, c = quad*8+j (+32) ----
    const int code  = biarr[myrow];
    const float* eb = embT32 + (code << 6) + (quad << 3);
    float4_t e0 = *(const float4_t*)(eb);          // c = quad*8 + 0..3
    float4_t e1 = *(const float4_t*)(eb + 4);      // c = quad*8 + 4..7
    float4_t e2 = *(const float4_t*)(eb + 32);     // c = 32 + quad*8 + 0..3
    float4_t e3 = *(const float4_t*)(eb + 36);     // c = 32 + quad*8 + 4..7
    float* qrow = out_q + ((size_t)b << 18) + hw0 + myrow;
    float sacc = 0.f;
#pragma unroll
    for (int j = 0; j < 4; ++j) {
        int c0 = (quad << 3) + j;
        int c1 = (quad << 3) + 4 + j;
        // chunk 0 (c < 32): frags ah0/al0
        float zA = bf2f((unsigned short)ah0[j])     + bf2f((unsigned short)al0[j]);
        float zB = bf2f((unsigned short)ah0[4 + j]) + bf2f((unsigned short)al0[4 + j]);
        float dA = e0[j] - zA, dB = e1[j] - zB;
        sacc += dA * dA + dB * dB;
        qrow[(size_t)c0 << 12] = e0[j];
        qrow[(size_t)c1 << 12] = e1[j];
        // chunk 1 (c >= 32): frags ah1/al1
        float zC = bf2f((unsigned short)ah1[j])     + bf2f((unsigned short)al1[j]);
        float zD = bf2f((unsigned short)ah1[4 + j]) + bf2f((unsigned short)al1[4 + j]);
        float dC = e2[j] - zC, dD = e3[j] - zD;
        sacc += dC * dC + dD * dD;
        qrow[(size_t)(32 + c0) << 12] = e2[j];
        qrow[(size_t)(32 + c1) << 12] = e3[j];
    }
#pragma unroll
    for (int off = 32; off > 0; off >>= 1)
        sacc += __shfl_down(sacc, off, 64);
    if (lane == 0) wsse[w] = sacc;
    __syncthreads();

    // ---- tail: regular SSE store + slotted relaxed hist atomics (no fence,
    //      no barrier after — ACK wait overlaps wave retirement) ----
    if (t == 0)
        ssepart[blockIdx.x] = (double)wsse[0] + (double)wsse[1]
                            + (double)wsse[2] + (double)wsse[3];
    if (t < ROWS_)
        __hip_atomic_fetch_add(&ghist8[((blockIdx.x & (NSLOT_ - 1)) << 9) + biarr[t]],
                               1, __ATOMIC_RELAXED, __HIP_MEMORY_SCOPE_AGENT);
}

// ---------------- finale: loss + perplexity (1 block) ----------------
__global__ __launch_bounds__(512) void vq_final(const int* __restrict__ ghist8,
                                                const double* __restrict__ ssepart,
                                                float* __restrict__ out_loss,
                                                float* __restrict__ out_perp) {
    __shared__ float  wsf[8];
    __shared__ double wsd[8];
    int t = threadIdx.x;
    int hsum = 0;
#pragma unroll
    for (int s8 = 0; s8 < NSLOT_; ++s8)
        hsum += ghist8[(s8 << 9) + t];    // coalesced over t
    float p = (float)hsum / (float)N_;
    float s = p * logf(p + 1e-10f);
    double d = ssepart[t] + ssepart[t + 512] + ssepart[t + 1024] + ssepart[t + 1536];
#pragma unroll
    for (int off = 32; off > 0; off >>= 1) {
        s += __shfl_down(s, off, 64);
        d += __shfl_down(d, off, 64);
    }
    if ((t & 63) == 0) { wsf[t >> 6] = s; wsd[t >> 6] = d; }
    __syncthreads();
    if (t == 0) {
        float  S = 0.f;
        double D = 0.0;
#pragma unroll
        for (int w = 0; w < 8; ++w) { S += wsf[w]; D += wsd[w]; }
        *out_perp = expf(-S);
        *out_loss = (float)(1.25 * D / (double)NC_);
    }
}

extern "C" void kernel_launch(void* const* d_in, const int* in_sizes, int n_in,
                              void* d_out, int out_size, void* d_ws, size_t ws_size,
                              hipStream_t stream) {
    const float* x   = (const float*)d_in[0];
    const float* emb = (const float*)d_in[1];

    float* out      = (float*)d_out;
    float* out_loss = out;
    float* out_q    = out + 1;
    float* out_perp = out + 1 + (size_t)N_ * C_;
    float* out_idx  = out + 2 + (size_t)N_ * C_;

    char* ws = (char*)d_ws;
    float*          snmax_p  = (float*)(ws + 56);
    float*          en       = (float*)(ws + 2112);
    float*          embT32   = (float*)(ws + 4160);
    unsigned short* fBhi     = (unsigned short*)(ws + 135232);
    unsigned short* fBlo     = (unsigned short*)(ws + 200768);
    int*            ghist8   = (int*)(ws + 266304);
    double*         ssepart  = (double*)(ws + 282688);

    vq_init<<<65, 512, 0, stream>>>(emb, snmax_p, en, embT32, fBhi, fBlo, ghist8);
    vq_argmin<<<NBLK_, 256, 0, stream>>>(x, en, embT32, fBhi, fBlo, snmax_p,
                                         out_q, out_idx, ghist8, ssepart);
    vq_final<<<1, 512, 0, stream>>>(ghist8, ssepart, out_loss, out_perp);
}